// Round 1
// baseline (2956.976 us; speedup 1.0000x reference)
//
#include <hip/hip_runtime.h>

// ChessBoardAttention on MI355X, fp32 end-to-end.
// ws layout (floats):
//   qsT [B*16][L][8]   offset 0        (589824)
//   ksT [B*16][L][8]   offset 589824   (589824)
//   vs  [B*16][64][L]  offset 1179648  (4718592)
// total 5,898,240 floats = 23.6 MB of d_ws.

#define LOG2E 1.44269504088896340736f

constexpr int B_ = 2, C_ = 64, C8_ = 8, H_ = 192, W_ = 192;
constexpr int HQ_ = 48, WQ_ = 48, L_ = HQ_ * WQ_;   // 2304
constexpr int TL = 128, TM = 64;
constexpr int NLT = L_ / TL;   // 18
constexpr int NMT = L_ / TM;   // 36

// ---------------------------------------------------------------------------
// Kernel 1: q/k/v projection fused with _offsets (chessboard gather + ReLU).
// One thread per (b, n, l) output token; loops over 64 input channels.
// Stores qsT/ksT transposed [l][8] (coalesced 32B/thread) and vs [c][l].
// ---------------------------------------------------------------------------
__global__ __launch_bounds__(256) void proj_kernel(
    const float* __restrict__ x,
    const float* __restrict__ Wq, const float* __restrict__ bq,
    const float* __restrict__ Wk, const float* __restrict__ bk,
    const float* __restrict__ Wv, const float* __restrict__ bv,
    float* __restrict__ qsT, float* __restrict__ ksT, float* __restrict__ vs)
{
    __shared__ float wqT[C_ * C8_];   // [c][o]
    __shared__ float wkT[C_ * C8_];   // [c][o]
    __shared__ float wvT[C_ * C_];    // [c][o]
    const int tid = threadIdx.x;
    for (int idx = tid; idx < C_ * C8_; idx += 256) {
        const int o = idx >> 6, c = idx & 63;
        wqT[c * C8_ + o] = Wq[idx];
        wkT[c * C8_ + o] = Wk[idx];
    }
    for (int idx = tid; idx < C_ * C_; idx += 256) {
        const int o = idx >> 6, c = idx & 63;
        wvT[c * C_ + o] = Wv[idx];
    }
    __syncthreads();

    const int gid = blockIdx.x * 256 + tid;       // (bn, l)
    const int bn = gid / L_;
    const int l  = gid - bn * L_;
    const int b = bn >> 4, n = bn & 15;
    const int h = (l / WQ_) * 4 + (n >> 2);
    const int w = (l % WQ_) * 4 + (n & 3);

    float aq[C8_] = {};
    float ak[C8_] = {};
    float av[C_] = {};
    const float* xp = x + ((size_t)(b * C_) * H_ + h) * W_ + w;

    #pragma unroll 8
    for (int c = 0; c < C_; ++c) {
        const float xv = xp[(size_t)c * (H_ * W_)];
        const float4 wq0 = *(const float4*)&wqT[c * C8_];
        const float4 wq1 = *(const float4*)&wqT[c * C8_ + 4];
        aq[0] += wq0.x * xv; aq[1] += wq0.y * xv; aq[2] += wq0.z * xv; aq[3] += wq0.w * xv;
        aq[4] += wq1.x * xv; aq[5] += wq1.y * xv; aq[6] += wq1.z * xv; aq[7] += wq1.w * xv;
        const float4 wk0 = *(const float4*)&wkT[c * C8_];
        const float4 wk1 = *(const float4*)&wkT[c * C8_ + 4];
        ak[0] += wk0.x * xv; ak[1] += wk0.y * xv; ak[2] += wk0.z * xv; ak[3] += wk0.w * xv;
        ak[4] += wk1.x * xv; ak[5] += wk1.y * xv; ak[6] += wk1.z * xv; ak[7] += wk1.w * xv;
        #pragma unroll
        for (int oo = 0; oo < 16; ++oo) {
            const float4 wv4 = *(const float4*)&wvT[c * C_ + 4 * oo];
            av[4 * oo + 0] += wv4.x * xv;
            av[4 * oo + 1] += wv4.y * xv;
            av[4 * oo + 2] += wv4.z * xv;
            av[4 * oo + 3] += wv4.w * xv;
        }
    }

    float r[C8_];
    #pragma unroll
    for (int o = 0; o < C8_; ++o) r[o] = fmaxf(aq[o] + bq[o], 0.f);
    float4* qdst = (float4*)(qsT + (size_t)gid * 8);
    qdst[0] = make_float4(r[0], r[1], r[2], r[3]);
    qdst[1] = make_float4(r[4], r[5], r[6], r[7]);

    #pragma unroll
    for (int o = 0; o < C8_; ++o) r[o] = fmaxf(ak[o] + bk[o], 0.f);
    float4* kdst = (float4*)(ksT + (size_t)gid * 8);
    kdst[0] = make_float4(r[0], r[1], r[2], r[3]);
    kdst[1] = make_float4(r[4], r[5], r[6], r[7]);

    float* vdst = vs + (size_t)bn * C_ * L_ + l;
    #pragma unroll
    for (int o = 0; o < C_; ++o)
        vdst[(size_t)o * L_] = fmaxf(av[o] + bv[o], 0.f);
}

// ---------------------------------------------------------------------------
// Kernel 2: fused attention per (b, n, 128-row Q tile).
// Scores bounded (ReLU'd inputs, 0.05-scale weights) -> softmax without max
// subtraction: accumulate unnormalized exp(s)*V and row sums, divide at end.
// LDS: Q[128][8], P[128][64] (xor-swizzled), V[64][64] (xor-swizzled).
// Stage 2: thread owns 4c x 8l accumulators; 8 b128 LDS reads per 128 FMA.
// ---------------------------------------------------------------------------
__global__ __launch_bounds__(256) void attn_kernel(
    const float* __restrict__ qsT, const float* __restrict__ ksT,
    const float* __restrict__ vs, const float* __restrict__ x,
    const float* __restrict__ gamma_p, float* __restrict__ out)
{
    __shared__ float Qs[TL * 8];       // [l][c]
    __shared__ float Ps[TL * TM];      // [l][m ^ swz(l)]
    __shared__ float Vs[C_ * TM];      // [c][m ^ swz(c)]
    __shared__ float rinv[TL];

    const int tid = threadIdx.x;
    const int bid = blockIdx.x;
    const int bn = bid / NLT;
    const int lt = bid - bn * NLT;
    const int b = bn >> 4, n = bn & 15;

    const float4* qb4 = (const float4*)(qsT + ((size_t)bn * L_ + lt * TL) * 8);
    const float4* kb4 = (const float4*)(ksT + (size_t)bn * L_ * 8);
    const float* vb = vs + (size_t)bn * C_ * L_;

    ((float4*)Qs)[tid] = qb4[tid];     // 256 * 16B = whole tile
    __syncthreads();

    // stage-1 (score) role: one key column m per thread, 32 rows each
    const int sm = tid & 63;
    const int lg = (tid >> 6) * 32;
    // stage-2 (PV) role: 4 channels x 8 rows
    const int c0 = (tid & 15) * 4;
    const int l0 = (tid >> 4) * 8;
    // V staging role
    const int vc = tid >> 2;
    const int vmo = (tid & 3) * 16;
    const int swv = ((vc >> 2) & 7) << 2;

    float acc[4][8] = {};
    float psum[32] = {};

    for (int mt = 0; mt < NMT; ++mt) {
        const int mb = mt * TM;

        // ---- stage V tile: global -> LDS (swizzled, coalesced 16 floats/thread)
        {
            const float* src = vb + (size_t)vc * L_ + mb + vmo;
            #pragma unroll
            for (int u = 0; u < 4; ++u) {
                const float4 v4 = *(const float4*)(src + 4 * u);
                *(float4*)&Vs[vc * TM + ((vmo + 4 * u) ^ swv)] = v4;
            }
        }
        // ---- stage P tile: scores + exp, accumulate row sums
        {
            const float4 k0 = kb4[(size_t)(mb + sm) * 2];
            const float4 k1 = kb4[(size_t)(mb + sm) * 2 + 1];
            #pragma unroll
            for (int li = 0; li < 32; ++li) {
                const int l = lg + li;
                const float4 q0 = *(const float4*)&Qs[l * 8];
                const float4 q1 = *(const float4*)&Qs[l * 8 + 4];
                const float s = q0.x * k0.x + q0.y * k0.y + q0.z * k0.z + q0.w * k0.w
                              + q1.x * k1.x + q1.y * k1.y + q1.z * k1.z + q1.w * k1.w;
                const float e = exp2f(s * LOG2E);
                Ps[l * TM + (sm ^ (((l >> 2) & 7) << 2))] = e;
                psum[li] += e;
            }
        }
        __syncthreads();

        // ---- stage 2: acc[c][l] += V[c][m] * P[l][m], vectorized over m by 4
        #pragma unroll
        for (int mm = 0; mm < TM; mm += 4) {
            float4 vv[4];
            float4 pp[8];
            #pragma unroll
            for (int i = 0; i < 4; ++i) {
                const int c = c0 + i;
                vv[i] = *(const float4*)&Vs[c * TM + (mm ^ (((c >> 2) & 7) << 2))];
            }
            #pragma unroll
            for (int j = 0; j < 8; ++j) {
                const int l = l0 + j;
                pp[j] = *(const float4*)&Ps[l * TM + (mm ^ (((l >> 2) & 7) << 2))];
            }
            #pragma unroll
            for (int i = 0; i < 4; ++i) {
                #pragma unroll
                for (int j = 0; j < 8; ++j) {
                    acc[i][j] += vv[i].x * pp[j].x + vv[i].y * pp[j].y
                               + vv[i].z * pp[j].z + vv[i].w * pp[j].w;
                }
            }
        }
        __syncthreads();
    }

    // ---- row softmax denominators: reduce psum across the wave's 64 key-columns
    #pragma unroll
    for (int li = 0; li < 32; ++li) {
        float s = psum[li];
        s += __shfl_xor(s, 1);
        s += __shfl_xor(s, 2);
        s += __shfl_xor(s, 4);
        s += __shfl_xor(s, 8);
        s += __shfl_xor(s, 16);
        s += __shfl_xor(s, 32);
        if (sm == li) rinv[lg + li] = 1.0f / s;
    }
    __syncthreads();

    // ---- epilogue: normalize, gamma * out + x, chessboard scatter
    const float g = gamma_p[0];
    #pragma unroll
    for (int j = 0; j < 8; ++j) {
        const int gl = lt * TL + l0 + j;
        const float ri = rinv[l0 + j];
        const int h = (gl / WQ_) * 4 + (n >> 2);
        const int w = (gl % WQ_) * 4 + (n & 3);
        #pragma unroll
        for (int i = 0; i < 4; ++i) {
            const int c = c0 + i;
            const size_t oidx = ((size_t)(b * C_ + c) * H_ + h) * W_ + w;
            out[oidx] = g * (acc[i][j] * ri) + x[oidx];
        }
    }
}

extern "C" void kernel_launch(void* const* d_in, const int* in_sizes, int n_in,
                              void* d_out, int out_size, void* d_ws, size_t ws_size,
                              hipStream_t stream) {
    const float* x  = (const float*)d_in[0];
    const float* Wq = (const float*)d_in[1];
    const float* bq = (const float*)d_in[2];
    const float* Wk = (const float*)d_in[3];
    const float* bk = (const float*)d_in[4];
    const float* Wv = (const float*)d_in[5];
    const float* bv = (const float*)d_in[6];
    const float* gamma = (const float*)d_in[7];
    float* out = (float*)d_out;

    float* ws  = (float*)d_ws;
    float* qsT = ws;                  // 589824 floats
    float* ksT = ws + 589824;         // 589824 floats
    float* vs  = ws + 1179648;        // 4718592 floats

    proj_kernel<<<dim3((B_ * 16 * L_) / 256), dim3(256), 0, stream>>>(
        x, Wq, bq, Wk, bk, Wv, bv, qsT, ksT, vs);
    attn_kernel<<<dim3(32 * NLT), dim3(256), 0, stream>>>(
        qsT, ksT, vs, x, gamma, out);
}

// Round 2
// 158.021 us; speedup vs baseline: 18.7125x; 18.7125x over previous
//
#include <hip/hip_runtime.h>

#define LOG2E 1.44269504088896340736f

constexpr int C_ = 64, H_ = 192, W_ = 192;
constexpr int WQ_ = 48, L_ = 2304;          // 48*48 tokens per offset
constexpr int KVB = 64;                      // key tile
constexpr int NMT = L_ / KVB;                // 36
constexpr int QROWS = 32;                    // q-rows per (1-wave) block
constexpr int NQT = L_ / QROWS;              // 72

typedef _Float16 half8  __attribute__((ext_vector_type(8)));
typedef short    bf16x8 __attribute__((ext_vector_type(8)));
typedef float    f32x16 __attribute__((ext_vector_type(16)));
typedef uint     u32x2  __attribute__((ext_vector_type(2)));
typedef uint     u32x4  __attribute__((ext_vector_type(4)));

static __device__ inline f32x16 fzero16() {
    f32x16 v;
    #pragma unroll
    for (int i = 0; i < 16; ++i) v[i] = 0.f;
    return v;
}

static __device__ inline uint cvtpk_bf16(float lo, float hi) {
    uint r;
    asm("v_cvt_pk_bf16_f32 %0, %1, %2" : "=v"(r) : "v"(lo), "v"(hi));
    return r;
}

static __device__ inline ushort f2bf(float f) {
    uint u = __builtin_bit_cast(uint, f);
    u = (u + 0x7FFFu + ((u >> 16) & 1u)) >> 16;
    return (ushort)u;
}

// ---------------------------------------------------------------------------
// Kernel 1: q/k/v projection fused with chessboard gather + ReLU.
// q stored as f16 pre-scaled by log2(e) (so scores feed exp2 directly),
// k as f16, v as bf16 [bn][c][l].
// ---------------------------------------------------------------------------
__global__ __launch_bounds__(256) void proj_kernel(
    const float* __restrict__ x,
    const float* __restrict__ Wq, const float* __restrict__ bq,
    const float* __restrict__ Wk, const float* __restrict__ bk,
    const float* __restrict__ Wv, const float* __restrict__ bv,
    _Float16* __restrict__ qh, _Float16* __restrict__ kh,
    ushort* __restrict__ vb)
{
    __shared__ float wqT[C_ * 8];
    __shared__ float wkT[C_ * 8];
    __shared__ float wvT[C_ * C_];
    const int tid = threadIdx.x;
    for (int idx = tid; idx < C_ * 8; idx += 256) {
        const int o = idx >> 6, c = idx & 63;
        wqT[c * 8 + o] = Wq[idx];
        wkT[c * 8 + o] = Wk[idx];
    }
    for (int idx = tid; idx < C_ * C_; idx += 256) {
        const int o = idx >> 6, c = idx & 63;
        wvT[c * C_ + o] = Wv[idx];
    }
    __syncthreads();

    const int gid = blockIdx.x * 256 + tid;       // (bn, l)
    const int bn = gid / L_;
    const int l  = gid - bn * L_;
    const int b = bn >> 4, n = bn & 15;
    const int h = (l / WQ_) * 4 + (n >> 2);
    const int w = (l % WQ_) * 4 + (n & 3);

    float aq[8] = {};
    float ak[8] = {};
    float av[C_] = {};
    const float* xp = x + ((size_t)(b * C_) * H_ + h) * W_ + w;

    #pragma unroll 8
    for (int c = 0; c < C_; ++c) {
        const float xv = xp[(size_t)c * (H_ * W_)];
        const float4 wq0 = *(const float4*)&wqT[c * 8];
        const float4 wq1 = *(const float4*)&wqT[c * 8 + 4];
        aq[0] += wq0.x * xv; aq[1] += wq0.y * xv; aq[2] += wq0.z * xv; aq[3] += wq0.w * xv;
        aq[4] += wq1.x * xv; aq[5] += wq1.y * xv; aq[6] += wq1.z * xv; aq[7] += wq1.w * xv;
        const float4 wk0 = *(const float4*)&wkT[c * 8];
        const float4 wk1 = *(const float4*)&wkT[c * 8 + 4];
        ak[0] += wk0.x * xv; ak[1] += wk0.y * xv; ak[2] += wk0.z * xv; ak[3] += wk0.w * xv;
        ak[4] += wk1.x * xv; ak[5] += wk1.y * xv; ak[6] += wk1.z * xv; ak[7] += wk1.w * xv;
        #pragma unroll
        for (int oo = 0; oo < 16; ++oo) {
            const float4 wv4 = *(const float4*)&wvT[c * C_ + 4 * oo];
            av[4 * oo + 0] += wv4.x * xv;
            av[4 * oo + 1] += wv4.y * xv;
            av[4 * oo + 2] += wv4.z * xv;
            av[4 * oo + 3] += wv4.w * xv;
        }
    }

    half8 qv, kv;
    #pragma unroll
    for (int o = 0; o < 8; ++o) {
        qv[o] = (_Float16)(fmaxf(aq[o] + bq[o], 0.f) * LOG2E);
        kv[o] = (_Float16)(fmaxf(ak[o] + bk[o], 0.f));
    }
    *(half8*)(qh + (size_t)gid * 8) = qv;
    *(half8*)(kh + (size_t)gid * 8) = kv;

    ushort* vd = vb + (size_t)bn * C_ * L_ + l;
    #pragma unroll
    for (int o = 0; o < C_; ++o)
        vd[(size_t)o * L_] = f2bf(fmaxf(av[o] + bv[o], 0.f));
}

// ---------------------------------------------------------------------------
// Kernel 2: one wave per (bn, 32 q-rows). MFMA flash-attention, no LDS.
//  - swapped QK^T: S^T = mfma_32x32x16_f16(Kfrag, Qfrag) -> lane holds one
//    q-row (col=lane&31) x 32 keys; K-dim 8 zero-padded to 16.
//  - exp2 (q pre-scaled), lane-local row sums (no max subtraction: inputs
//    ReLU'd, scores bounded; validated in fp32 round).
//  - P -> PV A-frags in-register: cvt_pk_bf16 + permlane32_swap (T12):
//    source m = 32h+8t+4hi'+q, frag m = 16ks+8hi+j  =>  hi'=j>>2, 4h+t=2ks+hi.
//  - V B-frags straight from global (L1/L2-cached), no staging.
// ---------------------------------------------------------------------------
__global__ __launch_bounds__(64) void attn_kernel(
    const _Float16* __restrict__ qh, const _Float16* __restrict__ kh,
    const ushort* __restrict__ vbuf, const float* __restrict__ x,
    const float* __restrict__ gamma_p, float* __restrict__ out)
{
    const int lane = threadIdx.x & 63;
    const int r32 = lane & 31;
    const int hi = lane >> 5;
    const int bid = blockIdx.x;
    const int bn = bid / NQT;
    const int lt = bid - bn * NQT;
    const int b = bn >> 4, n = bn & 15;
    const int qrow0 = lt * QROWS;

    const _Float16* qb = qh + (size_t)bn * L_ * 8;
    const _Float16* kb = kh + (size_t)bn * L_ * 8;
    const ushort*  vb = vbuf + (size_t)bn * C_ * L_;

    half8 qfrag;
    #pragma unroll
    for (int i = 0; i < 8; ++i) qfrag[i] = (_Float16)0.f;
    if (hi == 0) qfrag = *(const half8*)(qb + (size_t)(qrow0 + r32) * 8);

    f32x16 acc0 = fzero16(), acc1 = fzero16();
    float psum = 0.f;

    #pragma unroll 1
    for (int mt = 0; mt < NMT; ++mt) {
        const int mb = mt * KVB;

        half8 kf0, kf1;
        #pragma unroll
        for (int i = 0; i < 8; ++i) { kf0[i] = (_Float16)0.f; kf1[i] = (_Float16)0.f; }
        if (hi == 0) {
            kf0 = *(const half8*)(kb + (size_t)(mb + r32) * 8);
            kf1 = *(const half8*)(kb + (size_t)(mb + 32 + r32) * 8);
        }

        bf16x8 vf0[4], vf1[4];
        #pragma unroll
        for (int ks = 0; ks < 4; ++ks) {
            const int mo = mb + ks * 16 + hi * 8;
            vf0[ks] = *(const bf16x8*)(vb + (size_t)r32 * L_ + mo);
            vf1[ks] = *(const bf16x8*)(vb + (size_t)(32 + r32) * L_ + mo);
        }

        f32x16 s0 = __builtin_amdgcn_mfma_f32_32x32x16_f16(kf0, qfrag, fzero16(), 0, 0, 0);
        f32x16 s1 = __builtin_amdgcn_mfma_f32_32x32x16_f16(kf1, qfrag, fzero16(), 0, 0, 0);

        float p0[16], p1[16];
        #pragma unroll
        for (int r = 0; r < 16; ++r) p0[r] = __builtin_amdgcn_exp2f(s0[r]);
        #pragma unroll
        for (int r = 0; r < 16; ++r) p1[r] = __builtin_amdgcn_exp2f(s1[r]);
        #pragma unroll
        for (int r = 0; r < 16; ++r) psum += p0[r] + p1[r];

        // P -> A-frags: per kstep ks, sources idx0=2ks (lanes<32 side),
        // idx1=2ks+1 (lanes>=32 side); (h = idx>>2 selects p0/p1, t = idx&3).
        bf16x8 pa[4];
        #pragma unroll
        for (int ks = 0; ks < 4; ++ks) {
            const float* S = (ks < 2) ? p0 : p1;
            const int o0 = (ks & 1) * 8;
            const uint b0 = cvtpk_bf16(S[o0 + 0], S[o0 + 1]);
            const uint b1 = cvtpk_bf16(S[o0 + 2], S[o0 + 3]);
            const uint a0 = cvtpk_bf16(S[o0 + 4], S[o0 + 5]);
            const uint a1 = cvtpk_bf16(S[o0 + 6], S[o0 + 7]);
            const u32x2 r0 = __builtin_amdgcn_permlane32_swap(a0, b0, false, false);
            const u32x2 r1 = __builtin_amdgcn_permlane32_swap(a1, b1, false, false);
            u32x4 t;
            t[0] = r0.y; t[1] = r1.y; t[2] = r0.x; t[3] = r1.x;
            pa[ks] = __builtin_bit_cast(bf16x8, t);
        }

        #pragma unroll
        for (int ks = 0; ks < 4; ++ks) {
            acc0 = __builtin_amdgcn_mfma_f32_32x32x16_bf16(pa[ks], vf0[ks], acc0, 0, 0, 0);
            acc1 = __builtin_amdgcn_mfma_f32_32x32x16_bf16(pa[ks], vf1[ks], acc1, 0, 0, 0);
        }
    }

    // full row sums: lanes r and r+32 hold the two halves of row r
    const uint pu = __builtin_bit_cast(uint, psum);
    const u32x2 pc = __builtin_amdgcn_permlane32_swap(pu, pu, false, false);
    const float other = __builtin_bit_cast(float, (hi == 0) ? pc.x : pc.y);
    const float rinv = 1.0f / (psum + other);

    const float g = gamma_p[0];
    float rv[16];
    #pragma unroll
    for (int r = 0; r < 16; ++r) {
        const int R = (r & 3) + 8 * (r >> 2) + 4 * hi;   // D-layout row
        rv[r] = __shfl(rinv, R, 64);
    }

    #pragma unroll
    for (int r = 0; r < 16; ++r) {
        const int gl = qrow0 + (r & 3) + 8 * (r >> 2) + 4 * hi;
        const int hh = (gl / WQ_) * 4 + (n >> 2);
        const int ww = (gl % WQ_) * 4 + (n & 3);
        const size_t base = ((size_t)(b * C_) * H_ + hh) * W_ + ww;
        const size_t o0 = base + (size_t)r32 * (H_ * W_);
        out[o0] = g * (acc0[r] * rv[r]) + x[o0];
        const size_t o1 = base + (size_t)(32 + r32) * (H_ * W_);
        out[o1] = g * (acc1[r] * rv[r]) + x[o1];
    }
}

extern "C" void kernel_launch(void* const* d_in, const int* in_sizes, int n_in,
                              void* d_out, int out_size, void* d_ws, size_t ws_size,
                              hipStream_t stream) {
    const float* x  = (const float*)d_in[0];
    const float* Wq = (const float*)d_in[1];
    const float* bq = (const float*)d_in[2];
    const float* Wk = (const float*)d_in[3];
    const float* bk = (const float*)d_in[4];
    const float* Wv = (const float*)d_in[5];
    const float* bv = (const float*)d_in[6];
    const float* gamma = (const float*)d_in[7];
    float* out = (float*)d_out;

    // ws: qh (32*2304*8 f16) | kh (same) | vb (32*64*2304 bf16) = 11.8 MB
    _Float16* qh = (_Float16*)d_ws;
    _Float16* kh = qh + (size_t)32 * L_ * 8;
    ushort*   vb = (ushort*)(kh + (size_t)32 * L_ * 8);

    proj_kernel<<<dim3((32 * L_) / 256), dim3(256), 0, stream>>>(
        x, Wq, bq, Wk, bk, Wv, bv, qh, kh, vb);
    attn_kernel<<<dim3(32 * NQT), dim3(64), 0, stream>>>(
        qh, kh, vb, x, gamma, out);
}

// Round 3
// 138.580 us; speedup vs baseline: 21.3376x; 1.1403x over previous
//
#include <hip/hip_runtime.h>

#define LOG2E 1.44269504088896340736f

constexpr int C_ = 64, H_ = 192, W_ = 192;
constexpr int WQ_ = 48, L_ = 2304;          // 48*48 tokens per offset
constexpr int KVB = 64;                      // key tile
constexpr int NMT = L_ / KVB;                // 36 key tiles
constexpr int QROWS = 32;                    // q-rows per block
constexpr int NQT = L_ / QROWS;              // 72
constexpr int NBLK = 32 * NQT;               // 2304 attn blocks

typedef _Float16 half8  __attribute__((ext_vector_type(8)));
typedef short    bf16x8 __attribute__((ext_vector_type(8)));
typedef float    f32x16 __attribute__((ext_vector_type(16)));
typedef uint     u32x2  __attribute__((ext_vector_type(2)));
typedef uint     u32x4  __attribute__((ext_vector_type(4)));

static __device__ inline f32x16 fzero16() {
    f32x16 v;
    #pragma unroll
    for (int i = 0; i < 16; ++i) v[i] = 0.f;
    return v;
}

static __device__ inline uint cvtpk_bf16(float lo, float hi) {
    uint r;
    asm("v_cvt_pk_bf16_f32 %0, %1, %2" : "=v"(r) : "v"(lo), "v"(hi));
    return r;
}

static __device__ inline ushort f2bf(float f) {
    uint u = __builtin_bit_cast(uint, f);
    u = (u + 0x7FFFu + ((u >> 16) & 1u)) >> 16;
    return (ushort)u;
}

// ---------------------------------------------------------------------------
// Kernel 1: q/k/v projection fused with chessboard gather + ReLU.
// q: f16, pre-scaled by log2(e); k: f16, both [bn][l][8] (16B/token).
// v: bf16 in MFMA-B-fragment-tiled order [bn][mt][ks][ch][hi][j] so the attn
//    kernel's fragment loads are contiguous 1KB wave-loads.
// ---------------------------------------------------------------------------
__global__ __launch_bounds__(256) void proj_kernel(
    const float* __restrict__ x,
    const float* __restrict__ Wq, const float* __restrict__ bq,
    const float* __restrict__ Wk, const float* __restrict__ bk,
    const float* __restrict__ Wv, const float* __restrict__ bv,
    _Float16* __restrict__ qh, _Float16* __restrict__ kh,
    ushort* __restrict__ vws)
{
    __shared__ float wqT[C_ * 8];
    __shared__ float wkT[C_ * 8];
    __shared__ float wvT[C_ * C_];
    const int tid = threadIdx.x;
    for (int idx = tid; idx < C_ * 8; idx += 256) {
        const int o = idx >> 6, c = idx & 63;
        wqT[c * 8 + o] = Wq[idx];
        wkT[c * 8 + o] = Wk[idx];
    }
    for (int idx = tid; idx < C_ * C_; idx += 256) {
        const int o = idx >> 6, c = idx & 63;
        wvT[c * C_ + o] = Wv[idx];
    }
    __syncthreads();

    const int gid = blockIdx.x * 256 + tid;       // (bn, l)
    const int bn = gid / L_;
    const int l  = gid - bn * L_;
    const int b = bn >> 4, n = bn & 15;
    const int h = (l / WQ_) * 4 + (n >> 2);
    const int w = (l % WQ_) * 4 + (n & 3);

    float aq[8] = {};
    float ak[8] = {};
    float av[C_] = {};
    const float* xp = x + ((size_t)(b * C_) * H_ + h) * W_ + w;

    #pragma unroll 8
    for (int c = 0; c < C_; ++c) {
        const float xv = xp[(size_t)c * (H_ * W_)];
        const float4 wq0 = *(const float4*)&wqT[c * 8];
        const float4 wq1 = *(const float4*)&wqT[c * 8 + 4];
        aq[0] += wq0.x * xv; aq[1] += wq0.y * xv; aq[2] += wq0.z * xv; aq[3] += wq0.w * xv;
        aq[4] += wq1.x * xv; aq[5] += wq1.y * xv; aq[6] += wq1.z * xv; aq[7] += wq1.w * xv;
        const float4 wk0 = *(const float4*)&wkT[c * 8];
        const float4 wk1 = *(const float4*)&wkT[c * 8 + 4];
        ak[0] += wk0.x * xv; ak[1] += wk0.y * xv; ak[2] += wk0.z * xv; ak[3] += wk0.w * xv;
        ak[4] += wk1.x * xv; ak[5] += wk1.y * xv; ak[6] += wk1.z * xv; ak[7] += wk1.w * xv;
        #pragma unroll
        for (int oo = 0; oo < 16; ++oo) {
            const float4 wv4 = *(const float4*)&wvT[c * C_ + 4 * oo];
            av[4 * oo + 0] += wv4.x * xv;
            av[4 * oo + 1] += wv4.y * xv;
            av[4 * oo + 2] += wv4.z * xv;
            av[4 * oo + 3] += wv4.w * xv;
        }
    }

    half8 qv, kv;
    #pragma unroll
    for (int o = 0; o < 8; ++o) {
        qv[o] = (_Float16)(fmaxf(aq[o] + bq[o], 0.f) * LOG2E);
        kv[o] = (_Float16)(fmaxf(ak[o] + bk[o], 0.f));
    }
    *(half8*)(qh + (size_t)gid * 8) = qv;
    *(half8*)(kh + (size_t)gid * 8) = kv;

    // V fragment-tiled store: l -> (mt, ks, hi*8+j); channel stride = 16 elems
    const int mt = l >> 6;
    const int ks = (l >> 4) & 3;
    const int m16 = l & 15;                   // hi*8 + j
    ushort* vd = vws + ((((size_t)bn * NMT + mt) * 4 + ks) * 64) * 16 + m16;
    #pragma unroll
    for (int o = 0; o < C_; ++o)
        vd[o * 16] = f2bf(fmaxf(av[o] + bv[o], 0.f));
}

// ---------------------------------------------------------------------------
// Kernel 2: 128 threads = 2 waves per (bn, 32 q-rows); waves split the key
// tiles (even/odd) and combine partial acc/psum through LDS at the end.
//  - swapped QK^T: S^T = mfma_32x32x16_f16(Kfrag, Qfrag); K-dim 8 -> pad 16.
//  - exp2 (q pre-scaled), lane-local row sums, no max subtraction.
//  - P -> PV A-frags in-register: cvt_pk_bf16 + permlane32_swap.
//  - V B-frags: contiguous 1KB wave-loads from the fragment-tiled buffer.
// ---------------------------------------------------------------------------
__global__ __launch_bounds__(128) void attn_kernel(
    const _Float16* __restrict__ qh, const _Float16* __restrict__ kh,
    const ushort* __restrict__ vws, const float* __restrict__ x,
    const float* __restrict__ gamma_p, float* __restrict__ out)
{
    __shared__ float red[2][64][17];

    const int tid = threadIdx.x;
    const int wid = tid >> 6;
    const int lane = tid & 63;
    const int r32 = lane & 31;
    const int hi = lane >> 5;

    // XCD-bijective swizzle: 2304 blocks -> 288 contiguous per XCD
    const int bid0 = blockIdx.x;
    const int bid = (bid0 & 7) * (NBLK / 8) + (bid0 >> 3);
    const int bn = bid / NQT;
    const int lt = bid - bn * NQT;
    const int b = bn >> 4, n = bn & 15;
    const int qrow0 = lt * QROWS;

    const _Float16* qb = qh + (size_t)bn * L_ * 8;
    const _Float16* kb = kh + (size_t)bn * L_ * 8;
    const ushort* vtb = vws + (size_t)bn * NMT * 4096;

    half8 qfrag;
    #pragma unroll
    for (int i = 0; i < 8; ++i) qfrag[i] = (_Float16)0.f;
    if (hi == 0) qfrag = *(const half8*)(qb + (size_t)(qrow0 + r32) * 8);

    f32x16 acc0 = fzero16(), acc1 = fzero16();
    float psum = 0.f;

    #pragma unroll 1
    for (int t = 0; t < NMT / 2; ++t) {
        const int mt = 2 * t + wid;
        const int mb = mt * KVB;

        half8 kf0, kf1;
        #pragma unroll
        for (int i = 0; i < 8; ++i) { kf0[i] = (_Float16)0.f; kf1[i] = (_Float16)0.f; }
        if (hi == 0) {
            kf0 = *(const half8*)(kb + (size_t)(mb + r32) * 8);
            kf1 = *(const half8*)(kb + (size_t)(mb + 32 + r32) * 8);
        }

        const ushort* vt = vtb + (size_t)mt * 4096;
        bf16x8 vf0[4], vf1[4];
        #pragma unroll
        for (int ks = 0; ks < 4; ++ks) {
            vf0[ks] = *(const bf16x8*)(vt + ks * 1024 + r32 * 16 + hi * 8);
            vf1[ks] = *(const bf16x8*)(vt + ks * 1024 + (32 + r32) * 16 + hi * 8);
        }

        f32x16 s0 = __builtin_amdgcn_mfma_f32_32x32x16_f16(kf0, qfrag, fzero16(), 0, 0, 0);
        f32x16 s1 = __builtin_amdgcn_mfma_f32_32x32x16_f16(kf1, qfrag, fzero16(), 0, 0, 0);

        float p0[16], p1[16];
        #pragma unroll
        for (int r = 0; r < 16; ++r) p0[r] = __builtin_amdgcn_exp2f(s0[r]);
        #pragma unroll
        for (int r = 0; r < 16; ++r) p1[r] = __builtin_amdgcn_exp2f(s1[r]);
        #pragma unroll
        for (int r = 0; r < 16; ++r) psum += p0[r] + p1[r];

        // P -> A-frags (T12): idx = 2ks + side; h = idx>>2 picks p0/p1.
        bf16x8 pa[4];
        #pragma unroll
        for (int ks = 0; ks < 4; ++ks) {
            const float* S = (ks < 2) ? p0 : p1;
            const int o0 = (ks & 1) * 8;
            const uint b0 = cvtpk_bf16(S[o0 + 0], S[o0 + 1]);
            const uint b1 = cvtpk_bf16(S[o0 + 2], S[o0 + 3]);
            const uint a0 = cvtpk_bf16(S[o0 + 4], S[o0 + 5]);
            const uint a1 = cvtpk_bf16(S[o0 + 6], S[o0 + 7]);
            const u32x2 r0 = __builtin_amdgcn_permlane32_swap(a0, b0, false, false);
            const u32x2 r1 = __builtin_amdgcn_permlane32_swap(a1, b1, false, false);
            u32x4 tt;
            tt[0] = r0.y; tt[1] = r1.y; tt[2] = r0.x; tt[3] = r1.x;
            pa[ks] = __builtin_bit_cast(bf16x8, tt);
        }

        __builtin_amdgcn_s_setprio(1);
        #pragma unroll
        for (int ks = 0; ks < 4; ++ks) {
            acc0 = __builtin_amdgcn_mfma_f32_32x32x16_bf16(pa[ks], vf0[ks], acc0, 0, 0, 0);
            acc1 = __builtin_amdgcn_mfma_f32_32x32x16_bf16(pa[ks], vf1[ks], acc1, 0, 0, 0);
        }
        __builtin_amdgcn_s_setprio(0);
    }

    // per-wave full row sum (lanes r and r+32 hold the two key halves)
    const uint pu = __builtin_bit_cast(uint, psum);
    const u32x2 pc = __builtin_amdgcn_permlane32_swap(pu, pu, false, false);
    const float other = __builtin_bit_cast(float, (hi == 0) ? pc.x : pc.y);
    const float wsum = psum + other;

    // cross-wave combine: wave0 exports acc1 (ch 32-63), keeps acc0; wave1
    // exports acc0, keeps acc1. Each wave then owns one channel half.
    {
        float* dst = &red[wid][lane][0];
        const f32x16& ex = (wid == 0) ? acc1 : acc0;
        #pragma unroll
        for (int r = 0; r < 16; ++r) dst[r] = ex[r];
        dst[16] = wsum;
    }
    __syncthreads();

    const float* src = &red[wid ^ 1][lane][0];
    const float rtot = wsum + src[16];
    const float rinv = 1.0f / rtot;

    float fin[16];
    {
        const f32x16& keep = (wid == 0) ? acc0 : acc1;
        #pragma unroll
        for (int r = 0; r < 16; ++r) fin[r] = keep[r] + src[r];
    }

    float rv[16];
    #pragma unroll
    for (int r = 0; r < 16; ++r) {
        const int R = (r & 3) + 8 * (r >> 2) + 4 * hi;
        rv[r] = __shfl(rinv, R, 64);
    }

    const float g = gamma_p[0];
    const int ch = (wid == 0) ? r32 : (32 + r32);
    #pragma unroll
    for (int r = 0; r < 16; ++r) {
        const int gl = qrow0 + (r & 3) + 8 * (r >> 2) + 4 * hi;
        const int hh = (gl / WQ_) * 4 + (n >> 2);
        const int ww = (gl % WQ_) * 4 + (n & 3);
        const size_t o = ((size_t)(b * C_ + ch) * H_ + hh) * W_ + ww;
        out[o] = g * (fin[r] * rv[r]) + x[o];
    }
}

extern "C" void kernel_launch(void* const* d_in, const int* in_sizes, int n_in,
                              void* d_out, int out_size, void* d_ws, size_t ws_size,
                              hipStream_t stream) {
    const float* x  = (const float*)d_in[0];
    const float* Wq = (const float*)d_in[1];
    const float* bq = (const float*)d_in[2];
    const float* Wk = (const float*)d_in[3];
    const float* bk = (const float*)d_in[4];
    const float* Wv = (const float*)d_in[5];
    const float* bv = (const float*)d_in[6];
    const float* gamma = (const float*)d_in[7];
    float* out = (float*)d_out;

    // ws: qh (32*2304*8 f16) | kh (same) | v frag-tiled (32*36*4096 bf16)
    _Float16* qh = (_Float16*)d_ws;
    _Float16* kh = qh + (size_t)32 * L_ * 8;
    ushort*   vb = (ushort*)(kh + (size_t)32 * L_ * 8);

    proj_kernel<<<dim3((32 * L_) / 256), dim3(256), 0, stream>>>(
        x, Wq, bq, Wk, bk, Wv, bv, qh, kh, vb);
    attn_kernel<<<dim3(NBLK), dim3(128), 0, stream>>>(
        qh, kh, vb, x, gamma, out);
}

// Round 4
// 107.156 us; speedup vs baseline: 27.5951x; 1.2933x over previous
//
#include <hip/hip_runtime.h>

#define LOG2E 1.44269504088896340736f

constexpr int C_ = 64, H_ = 192, W_ = 192;
constexpr int WQ_ = 48, L_ = 2304;          // 48*48 tokens per offset
constexpr int KVB = 64;                      // key tile
constexpr int NMT = L_ / KVB;                // 36 key tiles
constexpr int QROWS = 32;                    // q-rows per block
constexpr int NQT = L_ / QROWS;              // 72
constexpr int NBLK = 32 * NQT;               // 2304 attn blocks
constexpr int WROW = 96;                     // padded wT row (floats)

typedef _Float16 half8  __attribute__((ext_vector_type(8)));
typedef short    bf16x8 __attribute__((ext_vector_type(8)));
typedef float    f32x16 __attribute__((ext_vector_type(16)));
typedef uint     u32x2  __attribute__((ext_vector_type(2)));
typedef uint     u32x4  __attribute__((ext_vector_type(4)));

static __device__ inline f32x16 fzero16() {
    f32x16 v;
    #pragma unroll
    for (int i = 0; i < 16; ++i) v[i] = 0.f;
    return v;
}

static __device__ inline uint cvtpk_bf16(float lo, float hi) {
    uint r;
    asm("v_cvt_pk_bf16_f32 %0, %1, %2" : "=v"(r) : "v"(lo), "v"(hi));
    return r;
}

static __device__ inline ushort f2bf(float f) {
    uint u = __builtin_bit_cast(uint, f);
    u = (u + 0x7FFFu + ((u >> 16) & 1u)) >> 16;
    return (ushort)u;
}

// ---------------------------------------------------------------------------
// Kernel 0: transpose weights into wT[c][96] (+ bias row) so the projection
// kernel can stream them through SGPRs (s_load) instead of LDS.
//   wT[c*96 + j]: j<64 -> Wv[j][c]; 64..71 -> log2e*Wq[j-64][c]; 72..79 -> Wk[j-72][c]
//   wT[64*96 + i]: i<64 -> bv[i]; 64..71 -> log2e*bq; 72..79 -> bk
// ---------------------------------------------------------------------------
__global__ __launch_bounds__(256) void wtrans_kernel(
    const float* __restrict__ Wq, const float* __restrict__ bq,
    const float* __restrict__ Wk, const float* __restrict__ bk,
    const float* __restrict__ Wv, const float* __restrict__ bv,
    float* __restrict__ wT)
{
    for (int idx = threadIdx.x; idx < 64 * WROW; idx += 256) {
        const int c = idx / WROW, j = idx - c * WROW;
        float v = 0.f;
        if (j < 64)      v = Wv[j * 64 + c];
        else if (j < 72) v = LOG2E * Wq[(j - 64) * 64 + c];
        else if (j < 80) v = Wk[(j - 72) * 64 + c];
        wT[idx] = v;
    }
    for (int i = threadIdx.x; i < WROW; i += 256) {
        float v = 0.f;
        if (i < 64)      v = bv[i];
        else if (i < 72) v = LOG2E * bq[i - 64];
        else if (i < 80) v = bk[i - 72];
        wT[64 * WROW + i] = v;
    }
}

// ---------------------------------------------------------------------------
// Kernel 1: q/k/v projection fused with chessboard gather + ReLU.
// Weights via wave-uniform loads (SGPR path) -> zero LDS traffic.
// q: f16 pre-scaled by log2e; k: f16; v: bf16 fragment-tiled
// [bn][mt][ks][ch][16] for contiguous attn B-frag loads.
// ---------------------------------------------------------------------------
__global__ __launch_bounds__(256) void proj_kernel(
    const float* __restrict__ x, const float* __restrict__ wTp,
    _Float16* __restrict__ qh, _Float16* __restrict__ kh,
    ushort* __restrict__ vws)
{
    const float* wT = (const float*)__builtin_assume_aligned(wTp, 64);
    const int gid = blockIdx.x * 256 + threadIdx.x;   // (bn, l)
    const int bn = gid / L_;
    const int l  = gid - bn * L_;
    const int b = bn >> 4, n = bn & 15;
    const int h = (l / WQ_) * 4 + (n >> 2);
    const int w = (l % WQ_) * 4 + (n & 3);

    const float* xp = x + ((size_t)(b * C_) * H_ + h) * W_ + w;

    float acc[80] = {};
    #pragma unroll 2
    for (int c = 0; c < C_; ++c) {
        const float xv = xp[(size_t)c * (H_ * W_)];
        const float4* wr4 = (const float4*)(wT + c * WROW);
        #pragma unroll
        for (int jj = 0; jj < 20; ++jj) {
            const float4 wv4 = wr4[jj];
            acc[4 * jj + 0] += wv4.x * xv;
            acc[4 * jj + 1] += wv4.y * xv;
            acc[4 * jj + 2] += wv4.z * xv;
            acc[4 * jj + 3] += wv4.w * xv;
        }
    }

    const float4* bias4 = (const float4*)(wT + 64 * WROW);

    // V fragment-tiled store: l -> (mt, ks, hi*8+j); channel stride = 16 elems
    const int mt = l >> 6;
    const int ks = (l >> 4) & 3;
    const int m16 = l & 15;
    ushort* vd = vws + (((size_t)bn * NMT + mt) * 4 + ks) * 1024 + m16;
    #pragma unroll
    for (int oo = 0; oo < 16; ++oo) {
        const float4 bb = bias4[oo];
        vd[(4 * oo + 0) * 16] = f2bf(fmaxf(acc[4 * oo + 0] + bb.x, 0.f));
        vd[(4 * oo + 1) * 16] = f2bf(fmaxf(acc[4 * oo + 1] + bb.y, 0.f));
        vd[(4 * oo + 2) * 16] = f2bf(fmaxf(acc[4 * oo + 2] + bb.z, 0.f));
        vd[(4 * oo + 3) * 16] = f2bf(fmaxf(acc[4 * oo + 3] + bb.w, 0.f));
    }

    const float* bias = wT + 64 * WROW;
    half8 qv, kv;
    #pragma unroll
    for (int o = 0; o < 8; ++o) {
        qv[o] = (_Float16)fmaxf(acc[64 + o] + bias[64 + o], 0.f);
        kv[o] = (_Float16)fmaxf(acc[72 + o] + bias[72 + o], 0.f);
    }
    *(half8*)(qh + (size_t)gid * 8) = qv;
    *(half8*)(kh + (size_t)gid * 8) = kv;
}

// ---------------------------------------------------------------------------
// Kernel 2: 256 threads = 4 waves per (bn, 32 q-rows); wave w handles KV
// tiles mt = 4t + w (9 each) and partials combine through LDS at the end.
//  - swapped QK^T: S^T = mfma_32x32x16_f16(Kfrag, Qfrag); K-dim 8 -> pad 16.
//  - exp2 (q pre-scaled), lane-local row sums, no max subtraction (inputs
//    ReLU'd, bounded scores; validated in fp32 round 1).
//  - P -> PV A-frags in-register: cvt_pk_bf16 + permlane32_swap (T12).
//  - V B-frags: contiguous 1KB wave-loads from the fragment-tiled buffer.
// ---------------------------------------------------------------------------
__global__ __launch_bounds__(256) void attn_kernel(
    const _Float16* __restrict__ qh, const _Float16* __restrict__ kh,
    const ushort* __restrict__ vws, const float* __restrict__ x,
    const float* __restrict__ gamma_p, float* __restrict__ out)
{
    __shared__ float red[4][64][17];

    const int tid = threadIdx.x;
    const int wid = tid >> 6;
    const int lane = tid & 63;
    const int r32 = lane & 31;
    const int hi = lane >> 5;

    // XCD-bijective swizzle: 2304 blocks -> 288 contiguous per XCD
    const int bid0 = blockIdx.x;
    const int bid = (bid0 & 7) * (NBLK / 8) + (bid0 >> 3);
    const int bn = bid / NQT;
    const int lt = bid - bn * NQT;
    const int b = bn >> 4, n = bn & 15;
    const int qrow0 = lt * QROWS;

    const _Float16* qb = qh + (size_t)bn * L_ * 8;
    const _Float16* kb = kh + (size_t)bn * L_ * 8;
    const ushort* vtb = vws + (size_t)bn * NMT * 4096;

    half8 qfrag;
    #pragma unroll
    for (int i = 0; i < 8; ++i) qfrag[i] = (_Float16)0.f;
    if (hi == 0) qfrag = *(const half8*)(qb + (size_t)(qrow0 + r32) * 8);

    f32x16 acc0 = fzero16(), acc1 = fzero16();
    float psum = 0.f;

    #pragma unroll 1
    for (int t = 0; t < NMT / 4; ++t) {
        const int mt = 4 * t + wid;
        const int mb = mt * KVB;

        half8 kf0, kf1;
        #pragma unroll
        for (int i = 0; i < 8; ++i) { kf0[i] = (_Float16)0.f; kf1[i] = (_Float16)0.f; }
        if (hi == 0) {
            kf0 = *(const half8*)(kb + (size_t)(mb + r32) * 8);
            kf1 = *(const half8*)(kb + (size_t)(mb + 32 + r32) * 8);
        }

        const ushort* vt = vtb + (size_t)mt * 4096;
        bf16x8 vf0[4], vf1[4];
        #pragma unroll
        for (int ks = 0; ks < 4; ++ks) {
            vf0[ks] = *(const bf16x8*)(vt + ks * 1024 + r32 * 16 + hi * 8);
            vf1[ks] = *(const bf16x8*)(vt + ks * 1024 + (32 + r32) * 16 + hi * 8);
        }

        f32x16 s0 = __builtin_amdgcn_mfma_f32_32x32x16_f16(kf0, qfrag, fzero16(), 0, 0, 0);
        f32x16 s1 = __builtin_amdgcn_mfma_f32_32x32x16_f16(kf1, qfrag, fzero16(), 0, 0, 0);

        float p0[16], p1[16];
        #pragma unroll
        for (int r = 0; r < 16; ++r) p0[r] = __builtin_amdgcn_exp2f(s0[r]);
        #pragma unroll
        for (int r = 0; r < 16; ++r) p1[r] = __builtin_amdgcn_exp2f(s1[r]);
        #pragma unroll
        for (int r = 0; r < 16; ++r) psum += p0[r] + p1[r];

        // P -> A-frags (T12): idx = 2ks + side; h = idx>>2 picks p0/p1.
        bf16x8 pa[4];
        #pragma unroll
        for (int ks = 0; ks < 4; ++ks) {
            const float* S = (ks < 2) ? p0 : p1;
            const int o0 = (ks & 1) * 8;
            const uint b0 = cvtpk_bf16(S[o0 + 0], S[o0 + 1]);
            const uint b1 = cvtpk_bf16(S[o0 + 2], S[o0 + 3]);
            const uint a0 = cvtpk_bf16(S[o0 + 4], S[o0 + 5]);
            const uint a1 = cvtpk_bf16(S[o0 + 6], S[o0 + 7]);
            const u32x2 r0 = __builtin_amdgcn_permlane32_swap(a0, b0, false, false);
            const u32x2 r1 = __builtin_amdgcn_permlane32_swap(a1, b1, false, false);
            u32x4 tt;
            tt[0] = r0.y; tt[1] = r1.y; tt[2] = r0.x; tt[3] = r1.x;
            pa[ks] = __builtin_bit_cast(bf16x8, tt);
        }

        __builtin_amdgcn_s_setprio(1);
        #pragma unroll
        for (int ks = 0; ks < 4; ++ks) {
            acc0 = __builtin_amdgcn_mfma_f32_32x32x16_bf16(pa[ks], vf0[ks], acc0, 0, 0, 0);
            acc1 = __builtin_amdgcn_mfma_f32_32x32x16_bf16(pa[ks], vf1[ks], acc1, 0, 0, 0);
        }
        __builtin_amdgcn_s_setprio(0);
    }

    // per-wave full row sum (lanes r and r+32 hold the two key halves)
    const uint pu = __builtin_bit_cast(uint, psum);
    const u32x2 pc = __builtin_amdgcn_permlane32_swap(pu, pu, false, false);
    const float other = __builtin_bit_cast(float, (hi == 0) ? pc.x : pc.y);
    const float wsum = psum + other;

    // ---- 4-way cross-wave combine through LDS (two rounds) ----
    // Round A: acc0 (channels 0..31) + wsum
    {
        float* dst = &red[wid][lane][0];
        #pragma unroll
        for (int r = 0; r < 16; ++r) dst[r] = acc0[r];
        dst[16] = wsum;
    }
    __syncthreads();

    float rtot = 0.f;
    #pragma unroll
    for (int w4 = 0; w4 < 4; ++w4) rtot += red[w4][lane][16];
    const float rinv = 1.0f / rtot;

    const int sw = wid & 1;           // sub-row half: r in [8*sw, 8*sw+8)
    float fin[8];
    if (wid < 2) {
        #pragma unroll
        for (int i = 0; i < 8; ++i)
            fin[i] = red[0][lane][8 * sw + i] + red[1][lane][8 * sw + i]
                   + red[2][lane][8 * sw + i] + red[3][lane][8 * sw + i];
    }
    __syncthreads();

    // Round B: acc1 (channels 32..63)
    {
        float* dst = &red[wid][lane][0];
        #pragma unroll
        for (int r = 0; r < 16; ++r) dst[r] = acc1[r];
    }
    __syncthreads();

    if (wid >= 2) {
        #pragma unroll
        for (int i = 0; i < 8; ++i)
            fin[i] = red[0][lane][8 * sw + i] + red[1][lane][8 * sw + i]
                   + red[2][lane][8 * sw + i] + red[3][lane][8 * sw + i];
    }

    // ---- epilogue: wave owns (ch-half, row-half); normalize + residual ----
    const int ch = r32 + ((wid >= 2) ? 32 : 0);
    const float g = gamma_p[0];
    #pragma unroll
    for (int i = 0; i < 8; ++i) {
        const int r = 8 * sw + i;
        const int R = (r & 3) + 8 * (r >> 2) + 4 * hi;
        const float ri = __shfl(rinv, R, 64);
        const int gl = qrow0 + R;
        const int hh = (gl / WQ_) * 4 + (n >> 2);
        const int ww = (gl % WQ_) * 4 + (n & 3);
        const size_t o = ((size_t)(b * C_ + ch) * H_ + hh) * W_ + ww;
        out[o] = g * (fin[i] * ri) + x[o];
    }
}

extern "C" void kernel_launch(void* const* d_in, const int* in_sizes, int n_in,
                              void* d_out, int out_size, void* d_ws, size_t ws_size,
                              hipStream_t stream) {
    const float* x  = (const float*)d_in[0];
    const float* Wq = (const float*)d_in[1];
    const float* bq = (const float*)d_in[2];
    const float* Wk = (const float*)d_in[3];
    const float* bk = (const float*)d_in[4];
    const float* Wv = (const float*)d_in[5];
    const float* bv = (const float*)d_in[6];
    const float* gamma = (const float*)d_in[7];
    float* out = (float*)d_out;

    // ws: wT (65*96 f32, pad 8192) | qh | kh | v frag-tiled
    float* wT = (float*)d_ws;
    _Float16* qh = (_Float16*)(wT + 8192);
    _Float16* kh = qh + (size_t)32 * L_ * 8;
    ushort*   vb = (ushort*)(kh + (size_t)32 * L_ * 8);

    wtrans_kernel<<<dim3(1), dim3(256), 0, stream>>>(Wq, bq, Wk, bk, Wv, bv, wT);
    proj_kernel<<<dim3((32 * L_) / 256), dim3(256), 0, stream>>>(x, wT, qh, kh, vb);
    attn_kernel<<<dim3(NBLK), dim3(256), 0, stream>>>(qh, kh, vb, x, gamma, out);
}

// Round 5
// 87.436 us; speedup vs baseline: 33.8189x; 1.2255x over previous
//
#include <hip/hip_runtime.h>

#define LOG2E 1.44269504088896340736f

constexpr int C_ = 64, H_ = 192, W_ = 192;
constexpr int WQ_ = 48, L_ = 2304;          // 48*48 tokens per offset
constexpr int KVB = 64;                      // key tile
constexpr int NMT = L_ / KVB;                // 36 key tiles
constexpr int QROWS = 32;                    // q-rows per block
constexpr int NQT = L_ / QROWS;              // 72
constexpr int NBLK = 32 * NQT;               // 2304 attn blocks
constexpr int WROW = 96;                     // padded wT row (floats)
constexpr int NCOL = 18432;                  // x float4-columns: 2*192*48
constexpr int PBLK = (NCOL / 64) * 4;        // proj blocks: 288 col-groups x 4 j

typedef _Float16 half8  __attribute__((ext_vector_type(8)));
typedef short    bf16x8 __attribute__((ext_vector_type(8)));
typedef float    f32x16 __attribute__((ext_vector_type(16)));
typedef uint     u32x2  __attribute__((ext_vector_type(2)));
typedef uint     u32x4  __attribute__((ext_vector_type(4)));

static __device__ inline f32x16 fzero16() {
    f32x16 v;
    #pragma unroll
    for (int i = 0; i < 16; ++i) v[i] = 0.f;
    return v;
}

static __device__ inline uint cvtpk_bf16(float lo, float hi) {
    uint r;
    asm("v_cvt_pk_bf16_f32 %0, %1, %2" : "=v"(r) : "v"(lo), "v"(hi));
    return r;
}

static __device__ inline ushort f2bf(float f) {
    uint u = __builtin_bit_cast(uint, f);
    u = (u + 0x7FFFu + ((u >> 16) & 1u)) >> 16;
    return (ushort)u;
}

// ---------------------------------------------------------------------------
// Kernel 0: transpose weights into wT[c][96] (+ bias row 64).
//   row c, col j: j<64 -> Wv[j][c]; 64..71 -> log2e*Wq[j-64][c]; 72..79 -> Wk[j-72][c]
// ---------------------------------------------------------------------------
__global__ __launch_bounds__(256) void wtrans_kernel(
    const float* __restrict__ Wq, const float* __restrict__ bq,
    const float* __restrict__ Wk, const float* __restrict__ bk,
    const float* __restrict__ Wv, const float* __restrict__ bv,
    float* __restrict__ wT)
{
    for (int idx = threadIdx.x; idx < 64 * WROW; idx += 256) {
        const int c = idx / WROW, j = idx - c * WROW;
        float v = 0.f;
        if (j < 64)      v = Wv[j * 64 + c];
        else if (j < 72) v = LOG2E * Wq[(j - 64) * 64 + c];
        else if (j < 80) v = Wk[(j - 72) * 64 + c];
        wT[idx] = v;
    }
    for (int i = threadIdx.x; i < WROW; i += 256) {
        float v = 0.f;
        if (i < 64)      v = bv[i];
        else if (i < 72) v = LOG2E * bq[i - 64];
        else if (i < 80) v = bk[i - 72];
        wT[64 * WROW + i] = v;
    }
}

// ---------------------------------------------------------------------------
// Kernel 1: projection + chessboard gather + ReLU, j-split.
// One 64-lane block per (column-group cg, j): lane = x-column C = cg*64+lane,
// C encodes (b, h, wq); token (bn = b*16 + 4*(h%4)+j, l = (h/4)*48+wq),
// x element at w = 4*wq + j. The 4 j-blocks of a cg are co-XCD (swizzle) so
// each 64B x line is fetched from HBM once and L2-shared. Weights are
// wave-uniform (SGPR loads). Thread computes 20 of the 80 outputs.
// ---------------------------------------------------------------------------
__global__ __launch_bounds__(64) void proj_kernel(
    const float* __restrict__ x, const float* __restrict__ wT,
    _Float16* __restrict__ qh, _Float16* __restrict__ kh,
    ushort* __restrict__ vws)
{
    const int bid0 = blockIdx.x;
    const int bid = (bid0 & 7) * (PBLK / 8) + (bid0 >> 3);  // 144 consecutive per XCD
    const int cg = bid >> 2;
    const int j  = bid & 3;
    const int lane = threadIdx.x;
    const int C = cg * 64 + lane;             // 0..18431
    const int b = C / 9216;
    const int cp = C - b * 9216;              // h*48 + wq
    const int h = cp / 48;
    const int wq = cp - h * 48;
    const int n = (h & 3) * 4 + j;
    const int l = (h >> 2) * 48 + wq;
    const int bn = b * 16 + n;

    const float* xp = x + (size_t)b * 64 * 36864 + cp * 4 + j;

    float acc[20] = {};
    #pragma unroll 4
    for (int c = 0; c < 64; ++c) {
        const float xv = xp[(size_t)c * 36864];
        const float4* w4 = (const float4*)(wT + c * WROW + j * 20);
        #pragma unroll
        for (int jj = 0; jj < 5; ++jj) {
            const float4 wv = w4[jj];
            acc[4 * jj + 0] += wv.x * xv;
            acc[4 * jj + 1] += wv.y * xv;
            acc[4 * jj + 2] += wv.z * xv;
            acc[4 * jj + 3] += wv.w * xv;
        }
    }

    const float* bias = wT + 64 * WROW;
    const int mt = l >> 6;
    const int ks4 = (l >> 4) & 3;
    const int m16 = l & 15;
    ushort* vd = vws + (((size_t)bn * NMT + mt) * 4 + ks4) * 1024 + m16;

    if (j < 3) {
        #pragma unroll
        for (int o = 0; o < 20; ++o)
            vd[(20 * j + o) * 16] = f2bf(fmaxf(acc[o] + bias[20 * j + o], 0.f));
    } else {
        #pragma unroll
        for (int o = 0; o < 4; ++o)
            vd[(60 + o) * 16] = f2bf(fmaxf(acc[o] + bias[60 + o], 0.f));
        half8 qv, kv;
        #pragma unroll
        for (int o = 0; o < 8; ++o) {
            qv[o] = (_Float16)fmaxf(acc[4 + o] + bias[64 + o], 0.f);
            kv[o] = (_Float16)fmaxf(acc[12 + o] + bias[72 + o], 0.f);
        }
        *(half8*)(qh + ((size_t)bn * L_ + l) * 8) = qv;
        *(half8*)(kh + ((size_t)bn * L_ + l) * 8) = kv;
    }
}

// ---------------------------------------------------------------------------
// Kernel 2: 4 waves per (bn, 32 q-rows), wave w owns KV tiles mt = 4t+w.
// Software-pipelined: kf(t+1) prefetched during tile t; vf(stage+1)
// prefetched during each ks stage's exp2/pack/MFMA. P streamed per-ks
// (8 exp2 -> cvt_pk/permlane pack -> 2 MFMA) to cap live registers.
// ---------------------------------------------------------------------------
__global__ __launch_bounds__(256) void attn_kernel(
    const _Float16* __restrict__ qh, const _Float16* __restrict__ kh,
    const ushort* __restrict__ vws, const float* __restrict__ x,
    const float* __restrict__ gamma_p, float* __restrict__ out)
{
    __shared__ float red[4][64][17];

    const int tid = threadIdx.x;
    const int wid = tid >> 6;
    const int lane = tid & 63;
    const int r32 = lane & 31;
    const int hi = lane >> 5;

    // XCD-bijective swizzle, bn-major chunks (K/V stay L2-resident per XCD)
    const int bid0 = blockIdx.x;
    const int bid = (bid0 & 7) * (NBLK / 8) + (bid0 >> 3);
    const int bn = bid / NQT;
    const int lt = bid - bn * NQT;
    const int b = bn >> 4, n = bn & 15;
    const int qrow0 = lt * QROWS;

    const _Float16* qb = qh + (size_t)bn * L_ * 8;
    const _Float16* kb = kh + (size_t)bn * L_ * 8;
    const ushort* vaddr = vws + (size_t)bn * NMT * 4096 + r32 * 16 + hi * 8;

    half8 qfrag;
    #pragma unroll
    for (int i = 0; i < 8; ++i) qfrag[i] = (_Float16)0.f;
    if (hi == 0) qfrag = *(const half8*)(qb + (qrow0 + r32) * 8);

    f32x16 acc0 = fzero16(), acc1 = fzero16();
    float psum = 0.f;

    half8 kf0c, kf1c, kf0n, kf1n;
    #pragma unroll
    for (int i = 0; i < 8; ++i) {
        kf0c[i] = (_Float16)0.f; kf1c[i] = (_Float16)0.f;
        kf0n[i] = (_Float16)0.f; kf1n[i] = (_Float16)0.f;
    }

    // prologue: tile t=0 loads
    {
        const int mt0 = wid;
        if (hi == 0) {
            kf0c = *(const half8*)(kb + (mt0 * 64 + r32) * 8);
            kf1c = *(const half8*)(kb + (mt0 * 64 + 32 + r32) * 8);
        }
    }
    bf16x8 v0c = *(const bf16x8*)(vaddr + wid * 4096);
    bf16x8 v1c = *(const bf16x8*)(vaddr + wid * 4096 + 512);

    #pragma unroll 1
    for (int t = 0; t < NMT / 4; ++t) {
        const int mt  = 4 * t + wid;
        const int mtn = (t < NMT / 4 - 1) ? mt + 4 : mt;   // clamped next tile

        if (hi == 0) {   // prefetch K for t+1 (masked; hi lanes stay zero)
            kf0n = *(const half8*)(kb + (mtn * 64 + r32) * 8);
            kf1n = *(const half8*)(kb + (mtn * 64 + 32 + r32) * 8);
        }

        const f32x16 s0 = __builtin_amdgcn_mfma_f32_32x32x16_f16(kf0c, qfrag, fzero16(), 0, 0, 0);
        const f32x16 s1 = __builtin_amdgcn_mfma_f32_32x32x16_f16(kf1c, qfrag, fzero16(), 0, 0, 0);

        #pragma unroll
        for (int ks = 0; ks < 4; ++ks) {
            // prefetch next stage's V frags
            const int noff = (ks < 3) ? (mt * 4096 + (ks + 1) * 1024) : (mtn * 4096);
            const bf16x8 nv0 = *(const bf16x8*)(vaddr + noff);
            const bf16x8 nv1 = *(const bf16x8*)(vaddr + noff + 512);

            // exp2 + row-sum + pack for this ks group
            float e[8];
            #pragma unroll
            for (int i = 0; i < 8; ++i) {
                const float sv = (ks < 2) ? s0[(ks & 1) * 8 + i] : s1[(ks & 1) * 8 + i];
                e[i] = __builtin_amdgcn_exp2f(sv);
            }
            #pragma unroll
            for (int i = 0; i < 8; ++i) psum += e[i];

            const uint b0 = cvtpk_bf16(e[0], e[1]);
            const uint b1 = cvtpk_bf16(e[2], e[3]);
            const uint a0 = cvtpk_bf16(e[4], e[5]);
            const uint a1 = cvtpk_bf16(e[6], e[7]);
            const u32x2 r0 = __builtin_amdgcn_permlane32_swap(a0, b0, false, false);
            const u32x2 r1 = __builtin_amdgcn_permlane32_swap(a1, b1, false, false);
            u32x4 tt;
            tt[0] = r0.y; tt[1] = r1.y; tt[2] = r0.x; tt[3] = r1.x;
            const bf16x8 pa = __builtin_bit_cast(bf16x8, tt);

            __builtin_amdgcn_s_setprio(1);
            acc0 = __builtin_amdgcn_mfma_f32_32x32x16_bf16(pa, v0c, acc0, 0, 0, 0);
            acc1 = __builtin_amdgcn_mfma_f32_32x32x16_bf16(pa, v1c, acc1, 0, 0, 0);
            __builtin_amdgcn_s_setprio(0);

            v0c = nv0; v1c = nv1;
        }
        kf0c = kf0n; kf1c = kf1n;
    }

    // per-wave full row sum (lanes r and r+32 hold the two key halves)
    const uint pu = __builtin_bit_cast(uint, psum);
    const u32x2 pc = __builtin_amdgcn_permlane32_swap(pu, pu, false, false);
    const float other = __builtin_bit_cast(float, (hi == 0) ? pc.x : pc.y);
    const float wsum = psum + other;

    // ---- 4-way cross-wave combine through LDS (two rounds) ----
    {
        float* dst = &red[wid][lane][0];
        #pragma unroll
        for (int r = 0; r < 16; ++r) dst[r] = acc0[r];
        dst[16] = wsum;
    }
    __syncthreads();

    float rtot = 0.f;
    #pragma unroll
    for (int w4 = 0; w4 < 4; ++w4) rtot += red[w4][lane][16];
    const float rinv = 1.0f / rtot;

    const int sw = wid & 1;           // sub-row half: r in [8*sw, 8*sw+8)
    float fin[8];
    if (wid < 2) {
        #pragma unroll
        for (int i = 0; i < 8; ++i)
            fin[i] = red[0][lane][8 * sw + i] + red[1][lane][8 * sw + i]
                   + red[2][lane][8 * sw + i] + red[3][lane][8 * sw + i];
    }
    __syncthreads();

    {
        float* dst = &red[wid][lane][0];
        #pragma unroll
        for (int r = 0; r < 16; ++r) dst[r] = acc1[r];
    }
    __syncthreads();

    if (wid >= 2) {
        #pragma unroll
        for (int i = 0; i < 8; ++i)
            fin[i] = red[0][lane][8 * sw + i] + red[1][lane][8 * sw + i]
                   + red[2][lane][8 * sw + i] + red[3][lane][8 * sw + i];
    }

    // ---- epilogue: wave owns (ch-half, row-half); normalize + residual ----
    const int ch = r32 + ((wid >= 2) ? 32 : 0);
    const float g = gamma_p[0];
    #pragma unroll
    for (int i = 0; i < 8; ++i) {
        const int r = 8 * sw + i;
        const int R = (r & 3) + 8 * (r >> 2) + 4 * hi;
        const float ri = __shfl(rinv, R, 64);
        const int gl = qrow0 + R;
        const int hh = (gl / WQ_) * 4 + (n >> 2);
        const int ww = (gl % WQ_) * 4 + (n & 3);
        const size_t o = ((size_t)(b * C_ + ch) * H_ + hh) * W_ + ww;
        out[o] = g * (fin[i] * ri) + x[o];
    }
}

extern "C" void kernel_launch(void* const* d_in, const int* in_sizes, int n_in,
                              void* d_out, int out_size, void* d_ws, size_t ws_size,
                              hipStream_t stream) {
    const float* x  = (const float*)d_in[0];
    const float* Wq = (const float*)d_in[1];
    const float* bq = (const float*)d_in[2];
    const float* Wk = (const float*)d_in[3];
    const float* bk = (const float*)d_in[4];
    const float* Wv = (const float*)d_in[5];
    const float* bv = (const float*)d_in[6];
    const float* gamma = (const float*)d_in[7];
    float* out = (float*)d_out;

    // ws: wT (65*96 f32, pad 8192) | qh | kh | v frag-tiled
    float* wT = (float*)d_ws;
    _Float16* qh = (_Float16*)(wT + 8192);
    _Float16* kh = qh + (size_t)32 * L_ * 8;
    ushort*   vb = (ushort*)(kh + (size_t)32 * L_ * 8);

    wtrans_kernel<<<dim3(1), dim3(256), 0, stream>>>(Wq, bq, Wk, bk, Wv, bv, wT);
    proj_kernel<<<dim3(PBLK), dim3(64), 0, stream>>>(x, wT, qh, kh, vb);
    attn_kernel<<<dim3(NBLK), dim3(256), 0, stream>>>(qh, kh, vb, x, gamma, out);
}

// Round 6
// 80.590 us; speedup vs baseline: 36.6918x; 1.0850x over previous
//
#include <hip/hip_runtime.h>

#define LOG2E 1.44269504088896340736f

constexpr int C_ = 64, H_ = 192, W_ = 192;
constexpr int WQ_ = 48, L_ = 2304;          // 48*48 tokens per offset
constexpr int KVB = 64;                      // key tile
constexpr int NMT = L_ / KVB;                // 36 key tiles
constexpr int QROWS = 32;                    // q-rows per block
constexpr int NQT = L_ / QROWS;              // 72
constexpr int NBLK = 32 * NQT;               // 2304 attn blocks
constexpr int WROW = 96;                     // padded wT row (floats)
constexpr int NCOL = 18432;                  // x float4-columns: 2*192*48
constexpr int PBLK = (NCOL / 64) * 4;        // proj blocks: 288 col-groups x 4 j

typedef _Float16 half8  __attribute__((ext_vector_type(8)));
typedef short    bf16x8 __attribute__((ext_vector_type(8)));
typedef float    f32x16 __attribute__((ext_vector_type(16)));
typedef uint     u32x2  __attribute__((ext_vector_type(2)));
typedef uint     u32x4  __attribute__((ext_vector_type(4)));

static __device__ inline f32x16 fzero16() {
    f32x16 v;
    #pragma unroll
    for (int i = 0; i < 16; ++i) v[i] = 0.f;
    return v;
}

static __device__ inline uint cvtpk_bf16(float lo, float hi) {
    uint r;
    asm("v_cvt_pk_bf16_f32 %0, %1, %2" : "=v"(r) : "v"(lo), "v"(hi));
    return r;
}

static __device__ inline ushort f2bf(float f) {
    uint u = __builtin_bit_cast(uint, f);
    u = (u + 0x7FFFu + ((u >> 16) & 1u)) >> 16;
    return (ushort)u;
}

// ---------------------------------------------------------------------------
// Kernel 0: transpose weights into wT[c][96] (+ bias row 64).
//   row c, col j: j<64 -> Wv[j][c]; 64..71 -> log2e*Wq[j-64][c]; 72..79 -> Wk[j-72][c]
// ---------------------------------------------------------------------------
__global__ __launch_bounds__(256) void wtrans_kernel(
    const float* __restrict__ Wq, const float* __restrict__ bq,
    const float* __restrict__ Wk, const float* __restrict__ bk,
    const float* __restrict__ Wv, const float* __restrict__ bv,
    float* __restrict__ wT)
{
    for (int idx = threadIdx.x; idx < 64 * WROW; idx += 256) {
        const int c = idx / WROW, j = idx - c * WROW;
        float v = 0.f;
        if (j < 64)      v = Wv[j * 64 + c];
        else if (j < 72) v = LOG2E * Wq[(j - 64) * 64 + c];
        else if (j < 80) v = Wk[(j - 72) * 64 + c];
        wT[idx] = v;
    }
    for (int i = threadIdx.x; i < WROW; i += 256) {
        float v = 0.f;
        if (i < 64)      v = bv[i];
        else if (i < 72) v = LOG2E * bq[i - 64];
        else if (i < 80) v = bk[i - 72];
        wT[64 * WROW + i] = v;
    }
}

// ---------------------------------------------------------------------------
// Kernel 1: projection + chessboard gather + ReLU, j-split.
// One 64-lane block per (column-group cg, j); x reads L2-shared across the
// 4 j-blocks (co-XCD via swizzle); weights wave-uniform (SGPR path).
// ---------------------------------------------------------------------------
__global__ __launch_bounds__(64) void proj_kernel(
    const float* __restrict__ x, const float* __restrict__ wT,
    _Float16* __restrict__ qh, _Float16* __restrict__ kh,
    ushort* __restrict__ vws)
{
    const int bid0 = blockIdx.x;
    const int bid = (bid0 & 7) * (PBLK / 8) + (bid0 >> 3);  // 144 consecutive per XCD
    const int cg = bid >> 2;
    const int j  = bid & 3;
    const int lane = threadIdx.x;
    const int C = cg * 64 + lane;             // 0..18431
    const int b = C / 9216;
    const int cp = C - b * 9216;              // h*48 + wq
    const int h = cp / 48;
    const int wq = cp - h * 48;
    const int n = (h & 3) * 4 + j;
    const int l = (h >> 2) * 48 + wq;
    const int bn = b * 16 + n;

    const float* xp = x + (size_t)b * 64 * 36864 + cp * 4 + j;

    float acc[20] = {};
    #pragma unroll 4
    for (int c = 0; c < 64; ++c) {
        const float xv = xp[(size_t)c * 36864];
        const float4* w4 = (const float4*)(wT + c * WROW + j * 20);
        #pragma unroll
        for (int jj = 0; jj < 5; ++jj) {
            const float4 wv = w4[jj];
            acc[4 * jj + 0] += wv.x * xv;
            acc[4 * jj + 1] += wv.y * xv;
            acc[4 * jj + 2] += wv.z * xv;
            acc[4 * jj + 3] += wv.w * xv;
        }
    }

    const float* bias = wT + 64 * WROW;
    const int mt = l >> 6;
    const int ks4 = (l >> 4) & 3;
    const int m16 = l & 15;
    ushort* vd = vws + (((size_t)bn * NMT + mt) * 4 + ks4) * 1024 + m16;

    if (j < 3) {
        #pragma unroll
        for (int o = 0; o < 20; ++o)
            vd[(20 * j + o) * 16] = f2bf(fmaxf(acc[o] + bias[20 * j + o], 0.f));
    } else {
        #pragma unroll
        for (int o = 0; o < 4; ++o)
            vd[(60 + o) * 16] = f2bf(fmaxf(acc[o] + bias[60 + o], 0.f));
        half8 qv, kv;
        #pragma unroll
        for (int o = 0; o < 8; ++o) {
            qv[o] = (_Float16)fmaxf(acc[4 + o] + bias[64 + o], 0.f);
            kv[o] = (_Float16)fmaxf(acc[12 + o] + bias[72 + o], 0.f);
        }
        *(half8*)(qh + ((size_t)bn * L_ + l) * 8) = qv;
        *(half8*)(kh + ((size_t)bn * L_ + l) * 8) = kv;
    }
}

// ---------------------------------------------------------------------------
// Kernel 2: 4 waves per (bn, 32 q-rows); wave w owns KV tiles mt = 4t+w.
// V prefetched 2 ks-stages ahead (static ring-4), K 1 tile ahead.
// Epilogue: in-LDS transpose -> minimal-line (8/instr) x-read + out-write.
// ---------------------------------------------------------------------------
__global__ __launch_bounds__(256) void attn_kernel(
    const _Float16* __restrict__ qh, const _Float16* __restrict__ kh,
    const ushort* __restrict__ vws, const float* __restrict__ x,
    const float* __restrict__ gamma_p, float* __restrict__ out)
{
    __shared__ float red[4][64][17];              // 17408 B; reused as lds_o[64][33]
    float* lds_o = &red[0][0][0];

    const int tid = threadIdx.x;
    const int wid = tid >> 6;
    const int lane = tid & 63;
    const int r32 = lane & 31;
    const int hi = lane >> 5;

    // XCD-bijective swizzle, bn-major chunks (K/V stay L2-resident per XCD)
    const int bid0 = blockIdx.x;
    const int bid = (bid0 & 7) * (NBLK / 8) + (bid0 >> 3);
    const int bn = bid / NQT;
    const int lt = bid - bn * NQT;
    const int b = bn >> 4, n = bn & 15;
    const int qrow0 = lt * QROWS;

    const _Float16* qb = qh + (size_t)bn * L_ * 8;
    const _Float16* kb = kh + (size_t)bn * L_ * 8;
    const ushort* vaddr = vws + (size_t)bn * NMT * 4096 + r32 * 16 + hi * 8;

    half8 qfrag;
    #pragma unroll
    for (int i = 0; i < 8; ++i) qfrag[i] = (_Float16)0.f;
    if (hi == 0) qfrag = *(const half8*)(qb + (qrow0 + r32) * 8);

    f32x16 acc0 = fzero16(), acc1 = fzero16();
    float psum = 0.f;

    half8 kf0c, kf1c, kf0n, kf1n;
    #pragma unroll
    for (int i = 0; i < 8; ++i) {
        kf0c[i] = (_Float16)0.f; kf1c[i] = (_Float16)0.f;
        kf0n[i] = (_Float16)0.f; kf1n[i] = (_Float16)0.f;
    }

    // prologue: tile t=0 K + V stages 0,1
    if (hi == 0) {
        kf0c = *(const half8*)(kb + (wid * 64 + r32) * 8);
        kf1c = *(const half8*)(kb + (wid * 64 + 32 + r32) * 8);
    }
    bf16x8 vb0[4], vb1[4];
    vb0[0] = *(const bf16x8*)(vaddr + wid * 4096);
    vb1[0] = *(const bf16x8*)(vaddr + wid * 4096 + 512);
    vb0[1] = *(const bf16x8*)(vaddr + wid * 4096 + 1024);
    vb1[1] = *(const bf16x8*)(vaddr + wid * 4096 + 1024 + 512);

    #pragma unroll 1
    for (int t = 0; t < NMT / 4; ++t) {
        const int mt  = 4 * t + wid;
        const int mtn = (t < NMT / 4 - 1) ? mt + 4 : mt;   // clamped next tile

        if (hi == 0) {   // prefetch K for t+1 (masked; hi lanes stay zero)
            kf0n = *(const half8*)(kb + (mtn * 64 + r32) * 8);
            kf1n = *(const half8*)(kb + (mtn * 64 + 32 + r32) * 8);
        }

        const f32x16 s0 = __builtin_amdgcn_mfma_f32_32x32x16_f16(kf0c, qfrag, fzero16(), 0, 0, 0);
        const f32x16 s1 = __builtin_amdgcn_mfma_f32_32x32x16_f16(kf1c, qfrag, fzero16(), 0, 0, 0);

        // stage KS: consume V slot KS, load V for stage KS+2 into slot LS.
        #define STAGE(KS, LS, LOFF)                                            \
        {                                                                      \
            const bf16x8 nv0 = *(const bf16x8*)(vaddr + (LOFF));               \
            const bf16x8 nv1 = *(const bf16x8*)(vaddr + (LOFF) + 512);         \
            float e[8];                                                        \
            _Pragma("unroll")                                                  \
            for (int i = 0; i < 8; ++i) {                                      \
                const float sv = (KS < 2) ? s0[(KS & 1) * 8 + i]               \
                                          : s1[(KS & 1) * 8 + i];              \
                e[i] = __builtin_amdgcn_exp2f(sv);                             \
            }                                                                  \
            psum += ((e[0] + e[1]) + (e[2] + e[3]))                            \
                  + ((e[4] + e[5]) + (e[6] + e[7]));                           \
            const uint pb0 = cvtpk_bf16(e[0], e[1]);                           \
            const uint pb1 = cvtpk_bf16(e[2], e[3]);                           \
            const uint pa0 = cvtpk_bf16(e[4], e[5]);                           \
            const uint pa1 = cvtpk_bf16(e[6], e[7]);                           \
            const u32x2 q0 = __builtin_amdgcn_permlane32_swap(pa0, pb0, false, false); \
            const u32x2 q1 = __builtin_amdgcn_permlane32_swap(pa1, pb1, false, false); \
            u32x4 tt;                                                          \
            tt[0] = q0.y; tt[1] = q1.y; tt[2] = q0.x; tt[3] = q1.x;            \
            const bf16x8 pa = __builtin_bit_cast(bf16x8, tt);                  \
            __builtin_amdgcn_s_setprio(1);                                     \
            acc0 = __builtin_amdgcn_mfma_f32_32x32x16_bf16(pa, vb0[KS], acc0, 0, 0, 0); \
            acc1 = __builtin_amdgcn_mfma_f32_32x32x16_bf16(pa, vb1[KS], acc1, 0, 0, 0); \
            __builtin_amdgcn_s_setprio(0);                                     \
            vb0[LS] = nv0; vb1[LS] = nv1;                                      \
        }

        STAGE(0, 2, mt * 4096 + 2048)
        STAGE(1, 3, mt * 4096 + 3072)
        STAGE(2, 0, mtn * 4096)
        STAGE(3, 1, mtn * 4096 + 1024)
        #undef STAGE

        kf0c = kf0n; kf1c = kf1n;
    }

    // per-wave full row sum (lanes r and r+32 hold the two key halves)
    const uint pu = __builtin_bit_cast(uint, psum);
    const u32x2 pc = __builtin_amdgcn_permlane32_swap(pu, pu, false, false);
    const float other = __builtin_bit_cast(float, (hi == 0) ? pc.x : pc.y);
    const float wsum = psum + other;

    // ---- 4-way cross-wave combine through LDS (two rounds) ----
    {
        float* dst = &red[wid][lane][0];
        #pragma unroll
        for (int r = 0; r < 16; ++r) dst[r] = acc0[r];
        dst[16] = wsum;
    }
    __syncthreads();

    float rtot = 0.f;
    #pragma unroll
    for (int w4 = 0; w4 < 4; ++w4) rtot += red[w4][lane][16];
    const float rinv = 1.0f / rtot;

    const int sw = wid & 1;           // sub-row half: r in [8*sw, 8*sw+8)
    float fin[8];
    if (wid < 2) {
        #pragma unroll
        for (int i = 0; i < 8; ++i)
            fin[i] = red[0][lane][8 * sw + i] + red[1][lane][8 * sw + i]
                   + red[2][lane][8 * sw + i] + red[3][lane][8 * sw + i];
    }
    __syncthreads();

    {
        float* dst = &red[wid][lane][0];
        #pragma unroll
        for (int r = 0; r < 16; ++r) dst[r] = acc1[r];
    }
    __syncthreads();

    if (wid >= 2) {
        #pragma unroll
        for (int i = 0; i < 8; ++i)
            fin[i] = red[0][lane][8 * sw + i] + red[1][lane][8 * sw + i]
                   + red[2][lane][8 * sw + i] + red[3][lane][8 * sw + i];
    }
    __syncthreads();

    // ---- in-LDS transpose: lds_o[ch][Rg] = normalized value ----
    {
        const int chw = r32 + ((wid >= 2) ? 32 : 0);
        #pragma unroll
        for (int i = 0; i < 8; ++i) {
            const int r = 8 * sw + i;
            const int Rg = (r & 3) + 8 * (r >> 2) + 4 * hi;
            const float ri = __shfl(rinv, Rg, 64);
            lds_o[chw * 33 + Rg] = fin[i] * ri;
        }
    }
    __syncthreads();

    // ---- minimal-line epilogue: lanes gl-major, 2 ch per instr ----
    const int gl = lane & 31;
    const int ch2 = lane >> 5;
    const int glf = qrow0 + gl;
    const int hh = (glf / WQ_) * 4 + (n >> 2);
    const int ww = (glf % WQ_) * 4 + (n & 3);
    const float g = gamma_p[0];
    const size_t base = ((size_t)b * C_ * H_ + hh) * W_ + ww;
    #pragma unroll
    for (int io = 0; io < 8; ++io) {
        const int ch = io * 8 + wid * 2 + ch2;
        const size_t o = base + (size_t)ch * (H_ * W_);
        out[o] = g * lds_o[ch * 33 + gl] + x[o];
    }
}

extern "C" void kernel_launch(void* const* d_in, const int* in_sizes, int n_in,
                              void* d_out, int out_size, void* d_ws, size_t ws_size,
                              hipStream_t stream) {
    const float* x  = (const float*)d_in[0];
    const float* Wq = (const float*)d_in[1];
    const float* bq = (const float*)d_in[2];
    const float* Wk = (const float*)d_in[3];
    const float* bk = (const float*)d_in[4];
    const float* Wv = (const float*)d_in[5];
    const float* bv = (const float*)d_in[6];
    const float* gamma = (const float*)d_in[7];
    float* out = (float*)d_out;

    // ws: wT (65*96 f32, pad 8192) | qh | kh | v frag-tiled
    float* wT = (float*)d_ws;
    _Float16* qh = (_Float16*)(wT + 8192);
    _Float16* kh = qh + (size_t)32 * L_ * 8;
    ushort*   vb = (ushort*)(kh + (size_t)32 * L_ * 8);

    wtrans_kernel<<<dim3(1), dim3(256), 0, stream>>>(Wq, bq, Wk, bk, Wv, bv, wT);
    proj_kernel<<<dim3(PBLK), dim3(64), 0, stream>>>(x, wT, qh, kh, vb);
    attn_kernel<<<dim3(NBLK), dim3(256), 0, stream>>>(qh, kh, vb, x, gamma, out);
}